// Round 5
// baseline (1097.076 us; speedup 1.0000x reference)
//
#include <hip/hip_runtime.h>

#define NP 16
#define D 768

// ws float layout:
//  [0, 12288)        PT[col][p]  (transposed, row-normalized prototypes)
//  [12288, 24576)    gsum[16][768]
//  [24576, 24592)    gcnt[16]

__global__ __launch_bounds__(64) void setup_kernel(const float* __restrict__ protos,
                                                   float* __restrict__ ws) {
    const int p = blockIdx.x;     // 0..15
    const int lane = threadIdx.x; // 0..63
    float* gsum = ws + 12288 + p * D;
    for (int j = lane; j < D; j += 64) gsum[j] = 0.f;
    if (lane == 0) ws[24576 + p] = 0.f;
    const float* pr = protos + p * D;
    float v[12];
    float ns = 0.f;
#pragma unroll
    for (int j = 0; j < 12; ++j) {
        v[j] = pr[lane + 64 * j];
        ns = fmaf(v[j], v[j], ns);
    }
#pragma unroll
    for (int m = 1; m < 64; m <<= 1) ns += __shfl_xor(ns, m);
    const float rn = 1.0f / sqrtf(ns);
#pragma unroll
    for (int j = 0; j < 12; ++j) ws[(lane + 64 * j) * NP + p] = v[j] * rn;  // PT[col][p]
}

// Per wave, per 64-row tile:
//   Phase A: lane = row. 24 chunks x 32 cols; each lane reads exactly its own
//            128B line per chunk (8 x float4, no LDS, no barriers -> loads
//            pipeline across chunks). Protos via provably-uniform scalar loads.
//   Phase B: row-at-a-time; assignment broadcast via readlane; all 64 lanes
//            re-read the row (float2, 512B/instr, LLC-hot) and ds_add into the
//            block-shared S[16][768] at stride-2 (2-way bank = free).
__global__ __launch_bounds__(256) void fused_kernel(const float* __restrict__ x,
                                                    const float* __restrict__ pt,
                                                    float* __restrict__ gsum,
                                                    float* __restrict__ gcnt,
                                                    int nrows, int ntiles) {
    __shared__ float S[NP * D];  // 48 KB block-level segment sums
    __shared__ float C[NP];

    const int tid = threadIdx.x;
    const int w = tid >> 6, lane = tid & 63;

    for (int i = tid; i < NP * D; i += 256) S[i] = 0.f;
    if (tid < NP) C[tid] = 0.f;
    __syncthreads();

    const int gw = blockIdx.x * 4 + w;  // global wave id
    const int NW = gridDim.x * 4;

    for (int tile = gw; tile < ntiles; tile += NW) {
        const int base = tile * 64;
        const int rows = min(64, nrows - base);

        // ---------- phase A: dots + norm + argmax (lane = row) ----------
        int rr = base + lane;
        if (rr >= nrows) rr = nrows - 1;
        const float* xr = x + (size_t)rr * D;

        float dacc[NP];
#pragma unroll
        for (int p = 0; p < NP; ++p) dacc[p] = 0.f;
        float ns = 0.f;

#pragma unroll 2
        for (int ch = 0; ch < 24; ++ch) {
            float4 xq[8];
#pragma unroll
            for (int q = 0; q < 8; ++q)
                xq[q] = *(const float4*)(xr + ch * 32 + q * 4);
            const float* pp = pt + ch * 32 * NP;  // uniform -> s_load
#pragma unroll
            for (int q = 0; q < 8; ++q) {
                const float xs[4] = {xq[q].x, xq[q].y, xq[q].z, xq[q].w};
#pragma unroll
                for (int e = 0; e < 4; ++e) {
                    const float xc = xs[e];
                    ns = fmaf(xc, xc, ns);
                    const float* pe = pp + (q * 4 + e) * NP;
#pragma unroll
                    for (int p = 0; p < NP; ++p) dacc[p] = fmaf(pe[p], xc, dacc[p]);
                }
            }
        }

        int a = 0;
        float bv = dacc[0];
#pragma unroll
        for (int p = 1; p < NP; ++p)
            if (dacc[p] > bv) { bv = dacc[p]; a = p; }
        const float rn = 1.0f / sqrtf(ns);

        // ---------- phase B: re-read tile (LLC-hot), accumulate ----------
        for (int r = 0; r < rows; ++r) {
            const int sa = __builtin_amdgcn_readlane(a, r);
            const float srn =
                __uint_as_float(__builtin_amdgcn_readlane(__float_as_uint(rn), r));
            const float* xrow = x + (size_t)(base + r) * D;
            float* dst = S + sa * D + lane * 2;
#pragma unroll
            for (int j = 0; j < 6; ++j) {
                const float2 v = *(const float2*)(xrow + lane * 2 + 128 * j);
                atomicAdd(&dst[128 * j + 0], v.x * srn);
                atomicAdd(&dst[128 * j + 1], v.y * srn);
            }
        }
        if (lane < rows) atomicAdd(&C[a], 1.0f);
    }

    __syncthreads();
    // flush block partials to global accumulators
    for (int i = tid; i < NP * D; i += 256)
        __hip_atomic_fetch_add(&gsum[i], S[i], __ATOMIC_RELAXED, __HIP_MEMORY_SCOPE_AGENT);
    if (tid < NP)
        __hip_atomic_fetch_add(&gcnt[tid], C[tid], __ATOMIC_RELAXED,
                               __HIP_MEMORY_SCOPE_AGENT);
}

__global__ __launch_bounds__(256) void finalize_kernel(const float* __restrict__ ws,
                                                       float* __restrict__ out) {
    const int i = blockIdx.x * blockDim.x + threadIdx.x;
    if (i < NP * D) {
        const int p = i / D;
        const float c = ws[24576 + p];
        const float s = ws[12288 + i];
        out[i] = (c > 0.f) ? s / fmaxf(c, 1.0f) : 0.f;
    }
}

extern "C" void kernel_launch(void* const* d_in, const int* in_sizes, int n_in,
                              void* d_out, int out_size, void* d_ws, size_t ws_size,
                              hipStream_t stream) {
    const float* x = (const float*)d_in[0];
    const float* protos = (const float*)d_in[1];
    float* ws = (float*)d_ws;
    float* out = (float*)d_out;
    const int nrows = in_sizes[0] / D;          // 200000
    const int ntiles = (nrows + 63) / 64;       // 3125

    setup_kernel<<<16, 64, 0, stream>>>(protos, ws);
    fused_kernel<<<768, 256, 0, stream>>>(x, ws, ws + 12288, ws + 24576, nrows, ntiles);
    finalize_kernel<<<(NP * D + 255) / 256, 256, 0, stream>>>(ws, out);
}

// Round 6
// 906.032 us; speedup vs baseline: 1.2109x; 1.2109x over previous
//
#include <hip/hip_runtime.h>

#define NP 16
#define D 768
#define NBLK 512
#define NTHR 256  // 4 waves

// ws float layout:
//  [0, 6144)                    PTfrag: [24 steps][64 lanes] x 8 ushort bf16 (24 KB)
//  [6144, 6144 + NBLK*12288)    per-block partial sums
//  [then NBLK*16]               per-block partial counts

typedef short short8 __attribute__((ext_vector_type(8)));
typedef float f32x4 __attribute__((ext_vector_type(4)));

static __device__ __forceinline__ short f2bf(float f) {
    unsigned u = __float_as_uint(f);
    u += 0x7FFF + ((u >> 16) & 1);  // RTNE
    return (short)(u >> 16);
}

__global__ __launch_bounds__(64) void setup_kernel(const float* __restrict__ protos,
                                                   float* __restrict__ ws) {
    const int p = blockIdx.x;     // 0..15
    const int lane = threadIdx.x; // 0..63
    const float* pr = protos + p * D;
    float v[12];
    float ns = 0.f;
#pragma unroll
    for (int j = 0; j < 12; ++j) {
        v[j] = pr[lane + 64 * j];
        ns = fmaf(v[j], v[j], ns);
    }
#pragma unroll
    for (int m = 1; m < 64; m <<= 1) ns += __shfl_xor(ns, m);
    const float rn = 1.0f / sqrtf(ns);
    // scatter into MFMA B-fragment order: value Pn[p][c], c = s*32 + g*8 + jj
    // stored at ushort index (s*64 + g*16 + p)*8 + jj
    unsigned short* ptf = (unsigned short*)ws;
#pragma unroll
    for (int j = 0; j < 12; ++j) {
        const int c = lane + 64 * j;
        const int s = c >> 5, sub = c & 31, g = sub >> 3, jj = sub & 7;
        ptf[(unsigned)((s * 64 + g * 16 + p) * 8 + jj)] = (unsigned short)f2bf(v[j] * rn);
    }
}

__global__ __launch_bounds__(NTHR) void fused_kernel(const float* __restrict__ x,
                                                     const float* __restrict__ ws,
                                                     float* __restrict__ gpart,
                                                     float* __restrict__ gcnt,
                                                     int nrows, int ntiles) {
    __shared__ float S[NP * D];       // 48 KB block-level segment sums
    __shared__ float C[NP];
    __shared__ short8 sPT[24 * 64];   // 24 KB proto fragments
    __shared__ int aStg[4][16];
    __shared__ float rStg[4][16];

    const int tid = threadIdx.x;
    const int w = tid >> 6, lane = tid & 63;

    {  // stage proto fragments + zero sums
        const uint4* src = (const uint4*)ws;
        uint4* dst = (uint4*)sPT;
        for (int i = tid; i < 1536; i += NTHR) dst[i] = src[i];
    }
    for (int i = tid; i < NP * D; i += NTHR) S[i] = 0.f;
    if (tid < NP) C[tid] = 0.f;
    __syncthreads();

    const int gw = blockIdx.x * 4 + w;
    const int NW = NBLK * 4;

    for (int tile = gw; tile < ntiles; tile += NW) {
        const int base = tile * 16;

        // ---------------- phase A: MFMA sim + fp32 norms ----------------
        const int rowc = min(base + (lane & 15), nrows - 1);
        const float* xr = x + (size_t)rowc * D + ((lane >> 4) << 3);
        const short8* bp = sPT + lane;

        f32x4 acc = {0.f, 0.f, 0.f, 0.f};
        float ns = 0.f;
#pragma unroll
        for (int s = 0; s < 24; ++s) {
            const float4 f0 = *(const float4*)(xr + s * 32);
            const float4 f1 = *(const float4*)(xr + s * 32 + 4);
            ns = fmaf(f0.x, f0.x, fmaf(f0.y, f0.y, fmaf(f0.z, f0.z, fmaf(f0.w, f0.w, ns))));
            ns = fmaf(f1.x, f1.x, fmaf(f1.y, f1.y, fmaf(f1.z, f1.z, fmaf(f1.w, f1.w, ns))));
            short8 af;
            af[0] = f2bf(f0.x); af[1] = f2bf(f0.y); af[2] = f2bf(f0.z); af[3] = f2bf(f0.w);
            af[4] = f2bf(f1.x); af[5] = f2bf(f1.y); af[6] = f2bf(f1.z); af[7] = f2bf(f1.w);
            const short8 bf = bp[s * 64];
            acc = __builtin_amdgcn_mfma_f32_16x16x32_bf16(af, bf, acc, 0, 0, 0);
        }

        // full row norm: reduce partials across the 4 lane-groups
        ns += __shfl_xor(ns, 16);
        ns += __shfl_xor(ns, 32);
        const float rn = 1.0f / sqrtf(ns);

        // argmax over protos: row = (lane>>4)*4 + r, proto = lane&15
        int ar[4];
#pragma unroll
        for (int r = 0; r < 4; ++r) {
            float bv = acc[r];
            int bi = lane & 15;
#pragma unroll
            for (int m = 1; m <= 8; m <<= 1) {
                const float ov = __shfl_xor(bv, m);
                const int oi = __shfl_xor(bi, m);
                if (ov > bv || (ov == bv && oi < bi)) { bv = ov; bi = oi; }
            }
            ar[r] = bi;
        }

        // stage per-row (assignment, rn) for phase B; bump counts
        if ((lane & 15) == 0) {
            const int rb = (lane >> 4) * 4;
#pragma unroll
            for (int r = 0; r < 4; ++r) {
                aStg[w][rb + r] = ar[r];
                if (base + rb + r < nrows) atomicAdd(&C[ar[r]], 1.0f);
            }
        }
        if (lane < 16) rStg[w][lane] = rn;

        // ---------------- phase B: cache-hot re-read, scatter ----------------
        const int rows = min(16, nrows - base);
#pragma unroll
        for (int half = 0; half < 2; ++half) {
            float2 v[8][6];
#pragma unroll
            for (int rr = 0; rr < 8; ++rr) {
                const int rowi = min(base + half * 8 + rr, nrows - 1);
                const float* xrow = x + (size_t)rowi * D + lane * 2;
#pragma unroll
                for (int j = 0; j < 6; ++j) v[rr][j] = *(const float2*)(xrow + j * 128);
            }
#pragma unroll
            for (int rr = 0; rr < 8; ++rr) {
                const int r = half * 8 + rr;
                if (r < rows) {
                    const int sa = aStg[w][r];
                    const float srn = rStg[w][r];
                    float* dstS = S + sa * D + lane * 2;
#pragma unroll
                    for (int j = 0; j < 6; ++j) {
                        atomicAdd(dstS + j * 128, v[rr][j].x * srn);
                        atomicAdd(dstS + j * 128 + 1, v[rr][j].y * srn);
                    }
                }
            }
        }
    }

    __syncthreads();
    // non-atomic flush: block-private partial slice
    float* gp = gpart + (size_t)blockIdx.x * (NP * D);
    for (int i = tid; i < NP * D; i += NTHR) gp[i] = S[i];
    if (tid < NP) gcnt[blockIdx.x * NP + tid] = C[tid];
}

__global__ __launch_bounds__(256) void finalize_kernel(const float* __restrict__ gpart,
                                                       const float* __restrict__ gcnt,
                                                       float* __restrict__ out) {
    __shared__ float cnt[NP];
    const int tid = threadIdx.x;
    if (tid < NP) {
        float c = 0.f;
        for (int b = 0; b < NBLK; ++b) c += gcnt[b * NP + tid];
        cnt[tid] = c;
    }
    __syncthreads();
    const int i = blockIdx.x * 256 + tid;
    if (i < NP * D) {
        float s = 0.f;
#pragma unroll 8
        for (int b = 0; b < NBLK; ++b) s += gpart[(size_t)b * (NP * D) + i];
        const float c = cnt[i / D];
        out[i] = (c > 0.f) ? s / fmaxf(c, 1.0f) : 0.f;
    }
}

extern "C" void kernel_launch(void* const* d_in, const int* in_sizes, int n_in,
                              void* d_out, int out_size, void* d_ws, size_t ws_size,
                              hipStream_t stream) {
    const float* x = (const float*)d_in[0];
    const float* protos = (const float*)d_in[1];
    float* ws = (float*)d_ws;
    float* out = (float*)d_out;
    const int nrows = in_sizes[0] / D;        // 200000
    const int ntiles = (nrows + 15) / 16;     // 12500

    float* gpart = ws + 6144;
    float* gcnt = ws + 6144 + (size_t)NBLK * (NP * D);

    setup_kernel<<<16, 64, 0, stream>>>(protos, ws);
    fused_kernel<<<NBLK, NTHR, 0, stream>>>(x, ws, gpart, gcnt, nrows, ntiles);
    finalize_kernel<<<(NP * D + 255) / 256, 256, 0, stream>>>(gpart, gcnt, out);
}